// Round 12
// baseline (133.351 us; speedup 1.0000x reference)
//
#include <hip/hip_runtime.h>

#define NPOS 4096
#define CDIM 256
#define FDIM 64

typedef short short8 __attribute__((ext_vector_type(8)));
typedef float f32x4 __attribute__((ext_vector_type(4)));

__device__ __forceinline__ unsigned short f2bf(float v) {
  unsigned u = __float_as_uint(v);
  unsigned r = (u + 0x7fffu + ((u >> 16) & 1u)) >> 16;  // RNE
  return (unsigned short)r;
}
__device__ __forceinline__ float bf2f(unsigned short u) {
  return __uint_as_float((unsigned)u << 16);
}
__device__ __forceinline__ short8 as_s8(uint4 u) {
  return *reinterpret_cast<short8*>(&u);
}
__device__ __forceinline__ void gload_lds16(const void* g, void* l) {
  __builtin_amdgcn_global_load_lds(
      (const __attribute__((address_space(1))) unsigned int*)g,
      (__attribute__((address_space(3))) unsigned int*)l, 16, 0, 0);
}

// ---------------------------------------------------------------------------
// Kernel 1: projections (unchanged from r10).
//   f planes pre-swizzled (chunk c of row r at c^(r&7)); g linear;
//   h_t = (x@Wh)^T bf16, pre-swizzled the same way.
// ---------------------------------------------------------------------------
__global__ __launch_bounds__(256) void proj_kernel(
    const float* __restrict__ x, const float* __restrict__ Wf,
    const float* __restrict__ Wg, const float* __restrict__ Wh,
    unsigned short* __restrict__ f_hi, unsigned short* __restrict__ f_lo,
    unsigned short* __restrict__ g_hi, unsigned short* __restrict__ g_lo,
    unsigned short* __restrict__ h_t) {
  __shared__ float xs[16][CDIM];
  const int row0 = blockIdx.x * 16;
  const int t = threadIdx.x;
  {
    const float4* xv = reinterpret_cast<const float4*>(x + (size_t)row0 * CDIM);
    float4* sv = reinterpret_cast<float4*>(&xs[0][0]);
#pragma unroll
    for (int i = 0; i < 4; ++i) sv[t + 256 * i] = xv[t + 256 * i];
  }
  __syncthreads();
  {
    float acc[16];
#pragma unroll
    for (int r = 0; r < 16; ++r) acc[r] = 0.f;
    for (int k = 0; k < CDIM; k += 4) {
      const float w0 = Wh[(size_t)(k + 0) * CDIM + t];
      const float w1 = Wh[(size_t)(k + 1) * CDIM + t];
      const float w2 = Wh[(size_t)(k + 2) * CDIM + t];
      const float w3 = Wh[(size_t)(k + 3) * CDIM + t];
#pragma unroll
      for (int r = 0; r < 16; ++r) {
        const float4 xv = *reinterpret_cast<const float4*>(&xs[r][k]);
        float a = acc[r];
        a = fmaf(xv.x, w0, a);
        a = fmaf(xv.y, w1, a);
        a = fmaf(xv.z, w2, a);
        a = fmaf(xv.w, w3, a);
        acc[r] = a;
      }
    }
    const int b = row0 >> 12;
    const int lr = row0 & (NPOS - 1);
    unsigned wd[8];
#pragma unroll
    for (int i = 0; i < 8; ++i)
      wd[i] = (unsigned)f2bf(acc[2 * i]) | ((unsigned)f2bf(acc[2 * i + 1]) << 16);
    uint4* base = reinterpret_cast<uint4*>(h_t + ((size_t)(b * CDIM + t)) * NPOS);
    const int m = t & 7;
    const int c0 = lr >> 3;   // even
    base[c0 ^ m] = make_uint4(wd[0], wd[1], wd[2], wd[3]);
    base[(c0 + 1) ^ m] = make_uint4(wd[4], wd[5], wd[6], wd[7]);
  }
  {
    const int col = t & 63;
    const int rb = (t >> 6) * 4;
    const int colq = col >> 3, cwi = col & 7;
    float af[4] = {0.f, 0.f, 0.f, 0.f};
    float ag[4] = {0.f, 0.f, 0.f, 0.f};
    for (int k = 0; k < CDIM; k += 4) {
      const float wf0 = Wf[(size_t)(k + 0) * FDIM + col];
      const float wf1 = Wf[(size_t)(k + 1) * FDIM + col];
      const float wf2 = Wf[(size_t)(k + 2) * FDIM + col];
      const float wf3 = Wf[(size_t)(k + 3) * FDIM + col];
      const float wg0 = Wg[(size_t)(k + 0) * FDIM + col];
      const float wg1 = Wg[(size_t)(k + 1) * FDIM + col];
      const float wg2 = Wg[(size_t)(k + 2) * FDIM + col];
      const float wg3 = Wg[(size_t)(k + 3) * FDIM + col];
#pragma unroll
      for (int r = 0; r < 4; ++r) {
        const float4 xv = *reinterpret_cast<const float4*>(&xs[rb + r][k]);
        float a = af[r], bb = ag[r];
        a = fmaf(xv.x, wf0, a); a = fmaf(xv.y, wf1, a);
        a = fmaf(xv.z, wf2, a); a = fmaf(xv.w, wf3, a);
        bb = fmaf(xv.x, wg0, bb); bb = fmaf(xv.y, wg1, bb);
        bb = fmaf(xv.z, wg2, bb); bb = fmaf(xv.w, wg3, bb);
        af[r] = a; ag[r] = bb;
      }
    }
#pragma unroll
    for (int r = 0; r < 4; ++r) {
      const int row = row0 + rb + r;
      const int ph = ((colq ^ (row & 7)) << 3) | cwi;
      const size_t of = (size_t)row * FDIM + ph;
      const size_t og = (size_t)row * FDIM + col;
      const unsigned short fh = f2bf(af[r]);
      const unsigned short gh = f2bf(ag[r]);
      f_hi[of] = fh;
      f_lo[of] = f2bf(af[r] - bf2f(fh));
      g_hi[og] = gh;
      g_lo[og] = f2bf(ag[r] - bf2f(gh));
    }
  }
}

// ---------------------------------------------------------------------------
// Kernel 2 (FUSED qk+pv, 16-row blocks): 512 threads / 8 waves, grid 512 ->
// 2 blocks/CU so the two barrier groups overlap each other's pipeline stalls
// (the r11 killer: grid 256 = 1 block/CU, all 16 waves stalled together at
// each of the 96 barriers).
// Phase A (r10 qk verbatim): s = g f^T (bf16x3, swapped), P=bf16(exp(s)) ->
//   2nd half of beta rows (swizzled); row sums -> LDS.
// Phase B (r10 pv geometry @16 rows): A(P)/B(h_t) DMA-staged GEMM; beta=P/l
//   fp32 in-stream; out = gamma*o/l + x.
// Barriers: s_waitcnt vmcnt(1) + raw s_barrier (own store excluded).
// ---------------------------------------------------------------------------
__global__ __launch_bounds__(512, 4) void attn_fused_kernel(
    const unsigned short* __restrict__ f_hi, const unsigned short* __restrict__ f_lo,
    const unsigned short* __restrict__ g_hi, const unsigned short* __restrict__ g_lo,
    const unsigned short* __restrict__ h_t, const float* __restrict__ x,
    const float* __restrict__ gamma, float* __restrict__ beta,
    float* __restrict__ out) {
  __shared__ __align__(16) char shraw[69632];  // A: Fh(32K)+Fl(32K); B: Ab(4K)+Bb(64K)
  __shared__ float partl[8][16];
  __shared__ float linvs[16];
  uint4 (*Fh)[128][8] = reinterpret_cast<uint4(*)[128][8]>(shraw);
  uint4 (*Fl)[128][8] = reinterpret_cast<uint4(*)[128][8]>(shraw + 32768);
  uint4 (*Ab)[16][8] = reinterpret_cast<uint4(*)[16][8]>(shraw);
  uint4 (*Bb)[256][8] = reinterpret_cast<uint4(*)[256][8]>(shraw + 4096);

  const int wg = blockIdx.x;
  const int wgid = (wg & 7) * 64 + (wg >> 3);   // bijective XCD chunking (512 wgs)
  const int b = wgid >> 8;
  const int row0 = (wgid & 255) * 16;
  const int t = threadIdx.x;
  const int w = t >> 6;     // 0..7
  const int l = t & 63;
  const int lr = l & 15;
  const int lk = l >> 4;

  // ============================ Phase A ============================
  const int arow = row0 + lr;     // this lane's beta row
  short8 gh[2], gl[2];
  {
    const unsigned short* gH = g_hi + ((size_t)(b * NPOS + arow)) * FDIM + lk * 8;
    const unsigned short* gL = g_lo + ((size_t)(b * NPOS + arow)) * FDIM + lk * 8;
#pragma unroll
    for (int ks = 0; ks < 2; ++ks) {
      gh[ks] = *reinterpret_cast<const short8*>(gH + ks * 32);
      gl[ks] = *reinterpret_cast<const short8*>(gL + ks * 32);
    }
  }
  const unsigned short* fbh = f_hi + (size_t)b * NPOS * FDIM;
  const unsigned short* fbl = f_lo + (size_t)b * NPOS * FDIM;
  unsigned short* Pb = (unsigned short*)(beta + (size_t)b * NPOS * NPOS);
  unsigned short* prow = Pb + (size_t)arow * (2 * NPOS) + NPOS;
  const int rsw = lr & 7;
  float lsum = 0.f;

#define STAGEA(buf, tile)                                                      \
  do {                                                                         \
    const int tile0_ = (tile) * 128;                                           \
    _Pragma("unroll")                                                          \
    for (int j = 0; j < 2; ++j) {                                              \
      const int slot_ = j * 512 + t;                                           \
      const int row_ = slot_ >> 3, ch_ = slot_ & 7;                            \
      gload_lds16(fbh + (size_t)(tile0_ + row_) * FDIM + ch_ * 8,              \
                  (char*)&Fh[buf][0][0] + (size_t)slot_ * 16);                 \
      gload_lds16(fbl + (size_t)(tile0_ + row_) * FDIM + ch_ * 8,              \
                  (char*)&Fl[buf][0][0] + (size_t)slot_ * 16);                 \
    }                                                                          \
  } while (0)

  STAGEA(0, 0);
  asm volatile("s_waitcnt vmcnt(0) lgkmcnt(0)\ns_barrier" ::: "memory");

  const int rrA = w * 16 + lr;    // A row within 128-col tile
  const int fsw = rrA & 7;
  int buf = 0;
  for (int tile = 0; tile < 32; ++tile) {
    if (tile < 31) STAGEA(buf ^ 1, tile + 1);
    __builtin_amdgcn_sched_barrier(0);   // pin gloads at top (vmcnt count safety)
    const uint4 h0 = Fh[buf][rrA][lk ^ fsw];
    const uint4 h1 = Fh[buf][rrA][(lk + 4) ^ fsw];
    const uint4 q0 = Fl[buf][rrA][lk ^ fsw];
    const uint4 q1 = Fl[buf][rrA][(lk + 4) ^ fsw];
    f32x4 acca = {0.f, 0.f, 0.f, 0.f};
    f32x4 accb = {0.f, 0.f, 0.f, 0.f};
    acca = __builtin_amdgcn_mfma_f32_16x16x32_bf16(as_s8(h0), gh[0], acca, 0, 0, 0);
    accb = __builtin_amdgcn_mfma_f32_16x16x32_bf16(as_s8(h0), gl[0], accb, 0, 0, 0);
    acca = __builtin_amdgcn_mfma_f32_16x16x32_bf16(as_s8(q0), gh[0], acca, 0, 0, 0);
    accb = __builtin_amdgcn_mfma_f32_16x16x32_bf16(as_s8(h1), gh[1], accb, 0, 0, 0);
    acca = __builtin_amdgcn_mfma_f32_16x16x32_bf16(as_s8(q1), gh[1], acca, 0, 0, 0);
    accb = __builtin_amdgcn_mfma_f32_16x16x32_bf16(as_s8(h1), gl[1], accb, 0, 0, 0);
    const f32x4 acc = acca + accb;
    const int cq = tile * 128 + w * 16 + lk * 4;   // 4 consecutive beta-cols
    const float e0 = __expf(acc[0]);
    const float e1 = __expf(acc[1]);
    const float e2 = __expf(acc[2]);
    const float e3 = __expf(acc[3]);
    lsum += (e0 + e1) + (e2 + e3);
    uint2 pk;
    pk.x = (unsigned)f2bf(e0) | ((unsigned)f2bf(e1) << 16);
    pk.y = (unsigned)f2bf(e2) | ((unsigned)f2bf(e3) << 16);
    const int sidx = (((cq >> 3) ^ rsw) << 3) | (cq & 7);
    *reinterpret_cast<uint2*>(prow + sidx) = pk;
    // counted barrier: drain this iter's gloads (fill buf^1, read next iter);
    // own P store (newest) stays in flight
    asm volatile("s_waitcnt vmcnt(1) lgkmcnt(0)\ns_barrier" ::: "memory");
    buf ^= 1;
  }
#undef STAGEA

  // row sums -> linvs (LDS only)
  lsum += __shfl_xor(lsum, 16);
  lsum += __shfl_xor(lsum, 32);
  if (l < 16) partl[w][l] = lsum;
  __syncthreads();
  if (t < 16) {
    float s = 0.f;
#pragma unroll
    for (int q = 0; q < 8; ++q) s += partl[q][t];
    linvs[t] = __frcp_rn(s);
  }
  // drain ALL P stores before Phase B's DMA re-reads them; publish linvs
  asm volatile("s_waitcnt vmcnt(0) lgkmcnt(0)\ns_barrier" ::: "memory");

  // ============================ Phase B ============================
  const size_t hoff = (size_t)b * CDIM * NPOS;
  const unsigned short* Pub = (const unsigned short*)(beta + (size_t)b * NPOS * NPOS);

#define STAGEB(buf, kt)                                                         \
  do {                                                                          \
    _Pragma("unroll")                                                           \
    for (int j = 0; j < 4; ++j) {                                               \
      const int slot_ = j * 512 + t;                                            \
      const unsigned short* g_ = h_t + hoff + (size_t)(slot_ >> 3) * NPOS +     \
                                 (size_t)((kt) * 8 + (slot_ & 7)) * 8;          \
      gload_lds16(g_, (char*)&Bb[buf][0][0] + (size_t)slot_ * 16);              \
    }                                                                           \
    if (t < 128) {                                                              \
      const unsigned short* g_ = Pub + (size_t)(row0 + (t >> 3)) * (2 * NPOS) + \
                                 NPOS + (size_t)((kt) * 8 + (t & 7)) * 8;       \
      gload_lds16(g_, (char*)&Ab[buf][0][0] + (size_t)t * 16);                  \
    }                                                                           \
  } while (0)

  f32x4 acc0 = {0.f, 0.f, 0.f, 0.f}, acc1 = {0.f, 0.f, 0.f, 0.f};
  const int c0 = w * 32 + lr;
  const int c1 = c0 + 16;
  const int brow = t >> 5;             // beta-write row 0..15
  const int jj = t & 31;               // beta-write k-pair

  STAGEB(0, 0);
  asm volatile("s_waitcnt vmcnt(0) lgkmcnt(0)\ns_barrier" ::: "memory");

  buf = 0;
  for (int kt = 0; kt < 64; ++kt) {
    if (kt < 63) STAGEB(buf ^ 1, kt + 1);
    __builtin_amdgcn_sched_barrier(0);   // pin gloads at top
    // ---- MFMA: K=64 as 2 k-steps of 32
    {
      const uint4 a0 = Ab[buf][lr][lk ^ (lr & 7)];
      const uint4 a1 = Ab[buf][lr][(4 + lk) ^ (lr & 7)];
      const uint4 b00 = Bb[buf][c0][lk ^ (c0 & 7)];
      const uint4 b01 = Bb[buf][c1][lk ^ (c1 & 7)];
      const uint4 b10 = Bb[buf][c0][(4 + lk) ^ (c0 & 7)];
      const uint4 b11 = Bb[buf][c1][(4 + lk) ^ (c1 & 7)];
      acc0 = __builtin_amdgcn_mfma_f32_16x16x32_bf16(as_s8(a0), as_s8(b00), acc0, 0, 0, 0);
      acc1 = __builtin_amdgcn_mfma_f32_16x16x32_bf16(as_s8(a0), as_s8(b01), acc1, 0, 0, 0);
      acc0 = __builtin_amdgcn_mfma_f32_16x16x32_bf16(as_s8(a1), as_s8(b10), acc0, 0, 0, 0);
      acc1 = __builtin_amdgcn_mfma_f32_16x16x32_bf16(as_s8(a1), as_s8(b11), acc1, 0, 0, 0);
    }
    // ---- beta write: 2 elems/thread from staged A tile
    {
      const float il = linvs[brow];
      const unsigned* arow_ = reinterpret_cast<const unsigned*>(&Ab[buf][brow][0]);
      const unsigned u = arow_[(((jj >> 2) ^ (brow & 7)) << 2) | (jj & 3)];
      float2 v;
      v.x = bf2f((unsigned short)(u & 0xffffu)) * il;
      v.y = bf2f((unsigned short)(u >> 16)) * il;
      *reinterpret_cast<float2*>(beta + (size_t)(b * NPOS + row0 + brow) * NPOS +
                                 (size_t)kt * 64 + jj * 2) = v;
    }
    // counted barrier: newest outstanding = the beta store
    asm volatile("s_waitcnt vmcnt(1) lgkmcnt(0)\ns_barrier" ::: "memory");
    buf ^= 1;
  }
#undef STAGEB

  // epilogue: out = gamma*o/l + x ; C/D: col=lane&15, row=(lane>>4)*4+reg
  const float gam = gamma[0];
#pragma unroll
  for (int r = 0; r < 4; ++r) {
    const int lrr = lk * 4 + r;
    const int orow = row0 + lrr;
    const float sc = gam * linvs[lrr];
    const size_t i0 = ((size_t)b * NPOS + orow) * CDIM + w * 32 + lr;
    out[i0] = fmaf(sc, acc0[r], x[i0]);
    out[i0 + 16] = fmaf(sc, acc1[r], x[i0 + 16]);
  }
}

extern "C" void kernel_launch(void* const* d_in, const int* in_sizes, int n_in,
                              void* d_out, int out_size, void* d_ws, size_t ws_size,
                              hipStream_t stream) {
  (void)in_sizes; (void)n_in; (void)out_size; (void)ws_size;
  const float* x = (const float*)d_in[0];
  const float* Wf = (const float*)d_in[1];
  const float* Wg = (const float*)d_in[2];
  const float* Wh = (const float*)d_in[3];
  const float* gamma = (const float*)d_in[4];

  float* out = (float*)d_out;                                   // [2*4096*256]
  float* beta = out + (size_t)2 * NPOS * CDIM;                  // [2*4096*4096]

  unsigned short* h_t = (unsigned short*)d_ws;                  // [2*256*4096]
  unsigned short* f_hi = h_t + (size_t)2 * CDIM * NPOS;         // [8192*64] each
  unsigned short* f_lo = f_hi + (size_t)2 * NPOS * FDIM;
  unsigned short* g_hi = f_lo + (size_t)2 * NPOS * FDIM;
  unsigned short* g_lo = g_hi + (size_t)2 * NPOS * FDIM;

  hipLaunchKernelGGL(proj_kernel, dim3(2 * NPOS / 16), dim3(256), 0, stream,
                     x, Wf, Wg, Wh, f_hi, f_lo, g_hi, g_lo, h_t);
  hipLaunchKernelGGL(attn_fused_kernel, dim3(512), dim3(512), 0, stream,
                     f_hi, f_lo, g_hi, g_lo, h_t, x, gamma, beta, out);
}